// Round 5
// baseline (357.452 us; speedup 1.0000x reference)
//
#include <hip/hip_runtime.h>

// DeltaQuantLinear: out[t,o] = sum_k x[t,k] * (base[o,k] + (q[o,k]-zp[o])*scale[o]) + bias[o]
// M=8 tokens, N=11008 out rows, K=4096. Memory-bound: 361 MB weights+q per call.
//
// R5: fix vmcnt issue-order bug. R4 issued wq[c+1] prefetch BEFORE x[c]; waiting
// for x[c] (newest) forced vmcnt(0), draining the prefetch -> no pipelining.
// Now: load x[c] (L2-resident) first, THEN issue wq[c+1] nt prefetch, then
// compute c -> compiler can wait at vmcnt(4), keeping prefetch in flight.
// RPB=2 (5504 blocks, tail-drain 2.3% at 512 resident) + LDS padded to 57 KB
// to pin 2 blocks/CU.

#define IN_F    4096
#define OUT_F   11008
#define TOKENS  8
#define RPB     2                 // output rows per block
#define THREADS 256
#define NBLOCKS (OUT_F / RPB)     // 5504

typedef float vf4 __attribute__((ext_vector_type(4)));
typedef int   vi4 __attribute__((ext_vector_type(4)));

__global__ __launch_bounds__(THREADS, 2)
void DeltaQuantLinear_87540023427416_kernel(
    const float* __restrict__ x,      // [8, 4096]
    const float* __restrict__ w,      // [11008, 4096]
    const int*   __restrict__ q,      // [11008, 4096]
    const float* __restrict__ scales, // [11008]
    const float* __restrict__ zps,    // [11008]
    const float* __restrict__ bias,   // [11008]
    float*       __restrict__ out)    // [8, 11008]
{
    // 57,344 B: first 16*257 floats = reduction scratch (stride-257, conflict-
    // free), next 256 = second-stage. Padded size pins occupancy to 2 blocks/CU.
    __shared__ float lds[14336];
    float* red  = lds;            // [16][257]
    float* red2 = lds + 16 * 257; // [16][16]

    const int tid = threadIdx.x;
    const int o0  = blockIdx.x * RPB;

    // per-row dequant constants (block-uniform)
    float s[RPB], c0[RPB];
#pragma unroll
    for (int r = 0; r < RPB; ++r) {
        const float sc = scales[o0 + r];
        s[r]  = sc;
        c0[r] = -zps[o0 + r] * sc;   // (q - zp)*s = q*s + c0
    }

    float acc[RPB][TOKENS];
#pragma unroll
    for (int r = 0; r < RPB; ++r)
#pragma unroll
        for (int t = 0; t < TOKENS; ++t) acc[r][t] = 0.0f;

    // Thread owns k = c*1024 + tid*4 + j (j in 0..3), c in 0..3.
    // Per wave: contiguous 1 KB dwordx4 loads for x, w, q.
    const float* wbase = w + (size_t)o0 * IN_F + tid * 4;
    const int*   qbase = q + (size_t)o0 * IN_F + tid * 4;

    vf4 wv[2][RPB];
    vi4 qv[2][RPB];

    // prefetch chunk 0 wq (HBM, nontemporal: read-once stream, keep x in L2)
#pragma unroll
    for (int r = 0; r < RPB; ++r) {
        wv[0][r] = __builtin_nontemporal_load((const vf4*)(wbase + (size_t)r * IN_F));
        qv[0][r] = __builtin_nontemporal_load((const vi4*)(qbase + (size_t)r * IN_F));
    }

#pragma unroll
    for (int c = 0; c < 4; ++c) {
        const int cur = c & 1;
        const int nxt = cur ^ 1;
        const int kbase = c * 1024 + tid * 4;

        // 1) x loads for THIS chunk first (L2-resident after first touch)
        vf4 xr[TOKENS];
#pragma unroll
        for (int t = 0; t < TOKENS; ++t)
            xr[t] = *(const vf4*)(x + t * IN_F + kbase);

        // 2) THEN issue next chunk's wq prefetch -> stays in flight while we
        //    wait for x and run the FMA body (vmcnt(4), not vmcnt(0))
        if (c < 3) {
            const int koff = (c + 1) * 1024;
#pragma unroll
            for (int r = 0; r < RPB; ++r) {
                wv[nxt][r] = __builtin_nontemporal_load((const vf4*)(wbase + (size_t)r * IN_F + koff));
                qv[nxt][r] = __builtin_nontemporal_load((const vi4*)(qbase + (size_t)r * IN_F + koff));
            }
        }

        // 3) compute chunk c
#pragma unroll
        for (int r = 0; r < RPB; ++r) {
#pragma unroll
            for (int j = 0; j < 4; ++j) {
                const float wfull = fmaf((float)qv[cur][r][j], s[r], wv[cur][r][j] + c0[r]);
#pragma unroll
                for (int t = 0; t < TOKENS; ++t)
                    acc[r][t] = fmaf(xr[t][j], wfull, acc[r][t]);
            }
        }
    }

    // Block reduction: 16 outputs (2 rows x 8 tokens), 256 partials each.
#pragma unroll
    for (int r = 0; r < RPB; ++r)
#pragma unroll
        for (int t = 0; t < TOKENS; ++t)
            red[(r * 8 + t) * 257 + tid] = acc[r][t];
    __syncthreads();

    {   // 16 threads per output, each sums 16 partials (stride-257: conflict-free)
        const int l = tid & 15;       // output index
        const int p = tid >> 4;       // partial group
        float sum = 0.0f;
        const float* row = &red[l * 257 + p * 16];
#pragma unroll
        for (int j = 0; j < 16; ++j) sum += row[j];
        red2[l * 16 + p] = sum;
    }
    __syncthreads();

    if (tid < 16) {
        float tot = 0.0f;
#pragma unroll
        for (int j = 0; j < 16; ++j) tot += red2[tid * 16 + j];
        const int r = tid >> 3;
        const int t = tid & 7;
        const int o = o0 + r;
        out[t * OUT_F + o] = tot + bias[o];
    }
}

extern "C" void kernel_launch(void* const* d_in, const int* in_sizes, int n_in,
                              void* d_out, int out_size, void* d_ws, size_t ws_size,
                              hipStream_t stream) {
    const float* x      = (const float*)d_in[0];
    const float* w      = (const float*)d_in[1];
    const int*   q      = (const int*)d_in[2];
    const float* scales = (const float*)d_in[3];
    const float* zps    = (const float*)d_in[4];
    const float* bias   = (const float*)d_in[5];
    float* out = (float*)d_out;

    DeltaQuantLinear_87540023427416_kernel<<<NBLOCKS, THREADS, 0, stream>>>(
        x, w, q, scales, zps, bias, out);
}